// Round 15
// baseline (539.860 us; speedup 1.0000x reference)
//
#include <hip/hip_runtime.h>

// Attention_11845519803093 — R21: no-LDS direct-fragment GEMMs; attn = R20 verbatim.
//   * gemm128n: per k-step, 8 MFMA fragments (A rows / B rows, 16B per lane)
//     loaded STRAIGHT from global (L2-hot fp16), batched, then 16 MFMAs.
//     Zero barriers, zero LDS — the transformation that took attn 581->264us.
//     Bit-identical numerics (same MFMA inputs as the staged version).
//   * attn unchanged (R20: srel-hoist + slim last tile, (256,2), VGPR 128).
// ws layout: qh | kh | vh | aoh | M2 | xh | wh | pwh

#define BB    16
#define NNq   577
#define DIMM  768
#define NHh   12
#define HD    64
#define MM    9232
#define QT    64
#define KT    64
#define NPAD  640
#define NW3   2304

typedef _Float16 h8 __attribute__((ext_vector_type(8)));
typedef _Float16 h4 __attribute__((ext_vector_type(4)));
typedef float    f4 __attribute__((ext_vector_type(4)));

__device__ inline h8 pack8(float4 a, float4 b) {
    h8 r;
    r[0]=(_Float16)a.x; r[1]=(_Float16)a.y; r[2]=(_Float16)a.z; r[3]=(_Float16)a.w;
    r[4]=(_Float16)b.x; r[5]=(_Float16)b.y; r[6]=(_Float16)b.z; r[7]=(_Float16)b.w;
    return r;
}

// ---------------------------------------------------------------- merged init
__global__ void init_all(const float* __restrict__ x, const float* __restrict__ w,
                         const float* __restrict__ pw,
                         _Float16* __restrict__ M2g, _Float16* __restrict__ vh,
                         _Float16* __restrict__ xh, _Float16* __restrict__ wh,
                         _Float16* __restrict__ pwh)
{
    const size_t id = (size_t)blockIdx.x*256 + threadIdx.x;
    if (id < NPAD*64) {
        const int key = (int)id >> 6, bin = (int)id & 63;
        int vb = 255, hb = 255;
        if (key == 0)      { vb = 24; hb = 49; }
        else if (key < NNq){ const int kq = key-1, kv = kq/24; vb = kv; hb = 25 + (kq - kv*24); }
        M2g[bin*NPAD + key] =
            ((key < NNq) && (bin==vb || bin==hb || bin==50)) ? (_Float16)1.f : (_Float16)0.f;
        return;
    }
    const size_t vid = id - NPAD*64;
    if (vid < (size_t)BB*NHh*HD*64) {
        const int head = (int)(vid >> 12);
        const int rem  = (int)vid & 4095;
        const int d    = rem >> 6;
        const int col  = 576 + (rem & 63);
        vh[(size_t)head*(HD*NPAD) + (size_t)d*NPAD + col] = (_Float16)0.f;
        return;
    }
    const size_t cid = vid - (size_t)BB*NHh*HD*64;
    const size_t NX = (size_t)MM*DIMM/4;
    const size_t NW = (size_t)NW3*DIMM/4;
    const size_t NP = (size_t)DIMM*DIMM/4;
    const float4* src; h4* dst; size_t j;
    if (cid < NX)            { src = (const float4*)x;  dst = (h4*)xh;  j = cid; }
    else if (cid < NX+NW)    { src = (const float4*)w;  dst = (h4*)wh;  j = cid - NX; }
    else if (cid < NX+NW+NP) { src = (const float4*)pw; dst = (h4*)pwh; j = cid - NX - NW; }
    else return;
    const float4 v = src[j];
    h4 hh; hh[0]=(_Float16)v.x; hh[1]=(_Float16)v.y; hh[2]=(_Float16)v.z; hh[3]=(_Float16)v.w;
    dst[j] = hh;
}

// ---------------------------------------------------------------- no-LDS direct-fragment GEMM
template <typename F>
__device__ __forceinline__ void gemm128n(const _Float16* __restrict__ Ah_g,
                                         const _Float16* __restrict__ Bh_g,
                                         F epi)
{
    const int t  = threadIdx.x;
    const int wv = t >> 6, lane = t & 63, lo = lane & 15, g = lane >> 4;
    const int wm = (wv >> 1) << 6, wn = (wv & 1) << 6;
    const int bm = blockIdx.y << 7, bn = blockIdx.x << 7;
    const int gb = g << 3;
    f4 acc[4][4] = {};

    // per-lane fragment row pointers (A rows clamped; garbage rows discarded in epi)
    const _Float16* ap[4];
    const _Float16* bp[4];
    #pragma unroll
    for (int mi = 0; mi < 4; ++mi) {
        int am = bm + wm + 16*mi + lo;
        if (am >= MM) am = MM - 1;
        ap[mi] = Ah_g + (size_t)am * DIMM + gb;
    }
    #pragma unroll
    for (int ni = 0; ni < 4; ++ni)
        bp[ni] = Bh_g + (size_t)(bn + wn + 16*ni + lo) * DIMM + gb;

    for (int k0 = 0; k0 < DIMM; k0 += 32) {
        h8 af[4], bf[4];
        #pragma unroll
        for (int mi = 0; mi < 4; ++mi) af[mi] = *(const h8*)(ap[mi] + k0);
        #pragma unroll
        for (int ni = 0; ni < 4; ++ni) bf[ni] = *(const h8*)(bp[ni] + k0);
        #pragma unroll
        for (int mi = 0; mi < 4; ++mi) {
            #pragma unroll
            for (int ni = 0; ni < 4; ++ni) {
                acc[mi][ni] = __builtin_amdgcn_mfma_f32_16x16x32_f16(af[mi], bf[ni], acc[mi][ni], 0, 0, 0);
            }
        }
    }
    epi(acc, bm, bn, wm, wn, lo, g);
}

// ---------------------------------------------------------------- QKV GEMM (no-LDS fp16)
__global__ __launch_bounds__(256, 2)
void qkv_gemm(const _Float16* __restrict__ xh, const _Float16* __restrict__ wh,
              _Float16* __restrict__ qh, _Float16* __restrict__ kh, _Float16* __restrict__ vh)
{
    gemm128n(xh, wh, [=](f4 (&acc)[4][4], int bm, int bn, int wm, int wn, int lo, int g) {
        const int three = bn / 768;
        const int cb    = bn - three * 768;
        #pragma unroll
        for (int mi = 0; mi < 4; ++mi) {
            #pragma unroll
            for (int reg = 0; reg < 4; ++reg) {
                const int m = bm + wm + 16*mi + 4*g + reg;
                if (m >= MM) continue;
                const int b_ = m / NNq;
                const int n_ = m - b_ * NNq;
                #pragma unroll
                for (int ni = 0; ni < 4; ++ni) {
                    const int n  = cb + wn + 16*ni + lo;
                    const int hh = n >> 6;
                    const int d  = n & 63;
                    if (three == 0) {
                        // Q scaled 0.125 * log2(e) for the exp2 path
                        qh[((size_t)(b_*NHh + hh)*NPAD + n_)*HD + d] =
                            (_Float16)(acc[mi][ni][reg] * 0.18033688f);
                    } else if (three == 1) {
                        kh[((size_t)(b_*NHh + hh)*NPAD + n_)*HD + d] = (_Float16)acc[mi][ni][reg];
                    } else {
                        vh[((size_t)(b_*NHh + hh)*HD + d)*NPAD + n_] = (_Float16)acc[mi][ni][reg];
                    }
                }
            }
        }
    });
}

// ---------------------------------------------------------------- proj GEMM (no-LDS fp16)
__global__ __launch_bounds__(256, 2)
void proj_gemm(const _Float16* __restrict__ aoh, const _Float16* __restrict__ pwh,
               const float* __restrict__ bias, float* __restrict__ out)
{
    gemm128n(aoh, pwh, [=](f4 (&acc)[4][4], int bm, int bn, int wm, int wn, int lo, int g) {
        #pragma unroll
        for (int ni = 0; ni < 4; ++ni) {
            const int n  = bn + wn + 16*ni + lo;
            const float bb = bias[n];
            #pragma unroll
            for (int mi = 0; mi < 4; ++mi) {
                #pragma unroll
                for (int reg = 0; reg < 4; ++reg) {
                    const int m = bm + wm + 16*mi + 4*g + reg;
                    if (m >= MM) continue;
                    out[(size_t)m*DIMM + n] = acc[mi][ni][reg] + bb;
                }
            }
        }
    });
}

// ---------------------------------------------------------------- fused attention (R20 verbatim)
__global__ __launch_bounds__(256, 2)
void attn_fused(const _Float16* __restrict__ qh,
                const _Float16* __restrict__ kh, const _Float16* __restrict__ vh,
                const float* __restrict__ tkv, const float* __restrict__ tkh,
                const float* __restrict__ tvv, const float* __restrict__ tvh,
                const _Float16* __restrict__ M2g,
                _Float16* __restrict__ aoh)
{
    __shared__ __align__(16) char smem[34048];
    _Float16 (*qrelS)[72] = (_Float16(*)[72])(smem);
    _Float16 (*Pt)[72]    = (_Float16(*)[72])(smem + 9216);
    float    (*TvS)[65]   = (float(*)[65])(smem + 18432);
    float    (*binsS)[52] = (float(*)[52])(smem);

    const int t    = threadIdx.x;
    const int w    = t >> 6;
    const int lane = t & 63;
    const int lo   = lane & 15;
    const int g    = lane >> 4;
    const int gb   = g << 3;

    const int blk = blockIdx.x;            // 0..1919
    const int x8  = blk & 7;
    const int r_  = blk >> 3;              // 0..239
    const int hq  = r_ / 10;               // 0..23
    const int qt  = r_ - hq*10;            // 0..9
    const int bh  = x8 + (hq << 3);        // head 0..191
    const int qt0 = qt * QT;
    const int qrow = 16*w + 4*g;
    const _Float16* qp = qh + (size_t)bh * (NPAD*HD);
    const _Float16* kp = kh + (size_t)bh * (NPAD*HD);
    const _Float16* vp = vh + (size_t)bh * (HD*NPAD);

    for (int e = t; e < 60*64; e += 256) {
        const int r = e >> 6, d = e & 63;
        TvS[r][d] = (r < 30) ? tvv[r*HD + d] : tvh[(r-30)*HD + d];
    }

    const h8 a0 = *(const h8*)(qp + (size_t)(qt0 + 16*w + lo)*HD + gb);
    const h8 a1 = *(const h8*)(qp + (size_t)(qt0 + 16*w + lo)*HD + 32 + gb);

    {
        f4 qacc[4] = {f4{0,0,0,0}, f4{0,0,0,0}, f4{0,0,0,0}, f4{0,0,0,0}};
        #pragma unroll
        for (int c = 0; c < 4; ++c) {
            const int r16 = 16*c + lo;
            const float* src = (r16 < 30) ? (tkv + r16*HD) : (tkh + (r16-30)*HD);
            h8 tb0 = {}, tb1 = {};
            if (r16 < 60) {
                tb0 = pack8(*(const float4*)(src + gb),      *(const float4*)(src + gb + 4));
                tb1 = pack8(*(const float4*)(src + 32 + gb), *(const float4*)(src + 32 + gb + 4));
            }
            qacc[c] = __builtin_amdgcn_mfma_f32_16x16x32_f16(a0, tb0, qacc[c], 0, 0, 0);
            qacc[c] = __builtin_amdgcn_mfma_f32_16x16x32_f16(a1, tb1, qacc[c], 0, 0, 0);
        }
        #pragma unroll
        for (int c = 0; c < 4; ++c) {
            #pragma unroll
            for (int i = 0; i < 4; ++i)
                qrelS[qrow + i][16*c + lo] = (_Float16)qacc[c][i];
        }
    }
    // NO barrier: gather below reads only this wave's own rows.

    int qv_[4], qh_[4];
    bool q0_[4];
    #pragma unroll
    for (int i = 0; i < 4; ++i) {
        const int qgl = qt0 + qrow + i;
        q0_[i] = (qgl == 0);
        int qq = qgl - 1; if (qq < 0) qq = 0;
        qv_[i] = qq / 24;
        qh_[i] = qq - qv_[i]*24;
    }

    f4 o_acc [4] = {f4{0,0,0,0}, f4{0,0,0,0}, f4{0,0,0,0}, f4{0,0,0,0}};
    f4 binacc[4] = {f4{0,0,0,0}, f4{0,0,0,0}, f4{0,0,0,0}, f4{0,0,0,0}};

    // ================= main loop: 9 full tiles (keys 0..575) =================
    for (int kt0 = 0; kt0 < 576; kt0 += KT) {
        h8 kb0[4], kb1[4], v0r[4], v1r[4], m20[4], m21[4];
        #pragma unroll
        for (int c = 0; c < 4; ++c) {
            const int key = kt0 + 16*c + lo;
            kb0[c] = *(const h8*)(kp + (size_t)key*HD + gb);
            kb1[c] = *(const h8*)(kp + (size_t)key*HD + 32 + gb);
            const int dd = 16*c + lo;
            v0r[c] = *(const h8*)(vp + (size_t)dd*NPAD + kt0 + gb);
            v1r[c] = *(const h8*)(vp + (size_t)dd*NPAD + kt0 + 32 + gb);
            m20[c] = *(const h8*)(M2g + (size_t)dd*NPAD + kt0 + gb);
            m21[c] = *(const h8*)(M2g + (size_t)dd*NPAD + kt0 + 32 + gb);
        }
        // ---- srel-hoist: LDS gather BEFORE the MFMAs (hides under vmcnt) ----
        float srel[4][4];
        #pragma unroll
        for (int c = 0; c < 4; ++c) {
            const int key = kt0 + 16*c + lo;
            int kk = key - 1; if (kk < 0) kk = 0;
            const int kv  = kk / 24;
            const int kh2 = kk - kv*24;
            const bool kz = (key == 0);
            #pragma unroll
            for (int i = 0; i < 4; ++i) {
                int colv, colh;
                if (kz || q0_[i]) { colv = 0; colh = 30; }
                else {
                    int dv = kv  - qv_[i]; dv = min(14, max(-14, dv));
                    int dh = kh2 - qh_[i]; dh = min(14, max(-14, dh));
                    colv = dv + 15;
                    colh = 45 + dh;
                }
                srel[c][i] = (float)qrelS[qrow+i][colv] + (float)qrelS[qrow+i][colh];
            }
        }
        f4 Sc[4];
        #pragma unroll
        for (int c = 0; c < 4; ++c) {
            f4 acc = f4{0,0,0,0};
            acc = __builtin_amdgcn_mfma_f32_16x16x32_f16(a0, kb0[c], acc, 0, 0, 0);
            acc = __builtin_amdgcn_mfma_f32_16x16x32_f16(a1, kb1[c], acc, 0, 0, 0);
            Sc[c] = acc;
        }
        #pragma unroll
        for (int c = 0; c < 4; ++c) {
            #pragma unroll
            for (int i = 0; i < 4; ++i) {
                const float p = exp2f(Sc[c][i] + srel[c][i]);
                Pt[qrow+i][16*c + lo] = (_Float16)p;
            }
        }
        const h8 p0 = *(const h8*)&Pt[16*w + lo][gb];
        const h8 p1 = *(const h8*)&Pt[16*w + lo][32 + gb];
        #pragma unroll
        for (int c = 0; c < 4; ++c) {
            binacc[c] = __builtin_amdgcn_mfma_f32_16x16x32_f16(p0, m20[c], binacc[c], 0, 0, 0);
            binacc[c] = __builtin_amdgcn_mfma_f32_16x16x32_f16(p1, m21[c], binacc[c], 0, 0, 0);
        }
        #pragma unroll
        for (int c = 0; c < 4; ++c) {
            o_acc[c] = __builtin_amdgcn_mfma_f32_16x16x32_f16(p0, v0r[c], o_acc[c], 0, 0, 0);
            o_acc[c] = __builtin_amdgcn_mfma_f32_16x16x32_f16(p1, v1r[c], o_acc[c], 0, 0, 0);
        }
    }

    // ================= slim last tile: kt0 = 576, 1 valid key =================
    {
        const int kt0 = 576;
        h8 kb0_, kb1_, v0r[4], v1r[4], m20[4], m21[4];
        kb0_ = *(const h8*)(kp + (size_t)(kt0 + lo)*HD + gb);
        kb1_ = *(const h8*)(kp + (size_t)(kt0 + lo)*HD + 32 + gb);
        #pragma unroll
        for (int c = 0; c < 4; ++c) {
            const int dd = 16*c + lo;
            v0r[c] = *(const h8*)(vp + (size_t)dd*NPAD + kt0 + gb);
            v1r[c] = *(const h8*)(vp + (size_t)dd*NPAD + kt0 + 32 + gb);
            m20[c] = *(const h8*)(M2g + (size_t)dd*NPAD + kt0 + gb);
            m21[c] = *(const h8*)(M2g + (size_t)dd*NPAD + kt0 + 32 + gb);
        }
        float srel0[4];
        {
            const int key = kt0 + lo;
            int kk = key - 1; if (kk < 0) kk = 0;
            const int kv  = kk / 24;
            const int kh2 = kk - kv*24;
            #pragma unroll
            for (int i = 0; i < 4; ++i) {
                int colv, colh;
                if (q0_[i]) { colv = 0; colh = 30; }
                else {
                    int dv = kv  - qv_[i]; dv = min(14, max(-14, dv));
                    int dh = kh2 - qh_[i]; dh = min(14, max(-14, dh));
                    colv = dv + 15;
                    colh = 45 + dh;
                }
                srel0[i] = (float)qrelS[qrow+i][colv] + (float)qrelS[qrow+i][colh];
            }
        }
        f4 Sc0 = f4{0,0,0,0};
        Sc0 = __builtin_amdgcn_mfma_f32_16x16x32_f16(a0, kb0_, Sc0, 0, 0, 0);
        Sc0 = __builtin_amdgcn_mfma_f32_16x16x32_f16(a1, kb1_, Sc0, 0, 0, 0);
        {
            const bool ok = (kt0 + lo) < NNq;
            #pragma unroll
            for (int i = 0; i < 4; ++i) {
                const float p = ok ? exp2f(Sc0[i] + srel0[i]) : 0.f;
                Pt[qrow+i][lo] = (_Float16)p;
            }
            #pragma unroll
            for (int c = 1; c < 4; ++c) {
                #pragma unroll
                for (int i = 0; i < 4; ++i)
                    Pt[qrow+i][16*c + lo] = (_Float16)0.f;
            }
        }
        const h8 p0 = *(const h8*)&Pt[16*w + lo][gb];
        const h8 p1 = *(const h8*)&Pt[16*w + lo][32 + gb];
        #pragma unroll
        for (int c = 0; c < 4; ++c) {
            binacc[c] = __builtin_amdgcn_mfma_f32_16x16x32_f16(p0, m20[c], binacc[c], 0, 0, 0);
            binacc[c] = __builtin_amdgcn_mfma_f32_16x16x32_f16(p1, m21[c], binacc[c], 0, 0, 0);
        }
        #pragma unroll
        for (int c = 0; c < 4; ++c) {
            o_acc[c] = __builtin_amdgcn_mfma_f32_16x16x32_f16(p0, v0r[c], o_acc[c], 0, 0, 0);
            o_acc[c] = __builtin_amdgcn_mfma_f32_16x16x32_f16(p1, v1r[c], o_acc[c], 0, 0, 0);
        }
    }

    // ---- epilogue ----
    __syncthreads();
    #pragma unroll
    for (int c = 0; c < 4; ++c) {
        const int bc = 16*c + lo;
        if (bc <= 50) {
            #pragma unroll
            for (int i = 0; i < 4; ++i) binsS[qrow+i][bc] = binacc[c][i];
        }
    }
    __syncthreads();

    const int b_ = bh / NHh;
    const int h_ = bh - b_*NHh;
    #pragma unroll
    for (int i = 0; i < 4; ++i) {
        const int qr  = qrow + i;
        const int qgl = qt0 + qr;
        if (qgl >= NNq) continue;
        const float l    = binsS[qr][50];
        const float invl = 1.f / l;
        float o[4] = {o_acc[0][i], o_acc[1][i], o_acc[2][i], o_acc[3][i]};
        if (qgl == 0) {
            #pragma unroll
            for (int c = 0; c < 4; ++c) {
                const int d = 16*c + lo;
                o[c] += l * (TvS[0][d] + TvS[30][d]);
            }
        } else {
            #pragma unroll
            for (int bin = 0; bin < 24; ++bin) {
                const float wq = binsS[qr][bin];
                int dv = bin - qv_[i]; dv = min(14, max(-14, dv));
                #pragma unroll
                for (int c = 0; c < 4; ++c) o[c] += wq * TvS[dv+15][16*c + lo];
            }
            {
                const float wq = binsS[qr][24];
                #pragma unroll
                for (int c = 0; c < 4; ++c) o[c] += wq * TvS[0][16*c + lo];
            }
            #pragma unroll
            for (int bin = 0; bin < 24; ++bin) {
                const float wq = binsS[qr][25+bin];
                int dh = bin - qh_[i]; dh = min(14, max(-14, dh));
                #pragma unroll
                for (int c = 0; c < 4; ++c) o[c] += wq * TvS[45+dh][16*c + lo];
            }
            {
                const float wq = binsS[qr][49];
                #pragma unroll
                for (int c = 0; c < 4; ++c) o[c] += wq * TvS[30][16*c + lo];
            }
        }
        _Float16* dst = aoh + (size_t)(b_*NNq + qgl)*DIMM + h_*HD;
        #pragma unroll
        for (int c = 0; c < 4; ++c) dst[16*c + lo] = (_Float16)(o[c] * invl);
    }
}

// ---------------------------------------------------------------- launcher
extern "C" void kernel_launch(void* const* d_in, const int* in_sizes, int n_in,
                              void* d_out, int out_size, void* d_ws, size_t ws_size,
                              hipStream_t stream)
{
    const float* x      = (const float*)d_in[0];
    const float* qkv_w  = (const float*)d_in[1];
    const float* proj_w = (const float*)d_in[2];
    const float* proj_b = (const float*)d_in[3];
    const float* tkv    = (const float*)d_in[4];
    const float* tkh    = (const float*)d_in[5];
    const float* tvv    = (const float*)d_in[6];
    const float* tvh    = (const float*)d_in[7];
    float* out = (float*)d_out;
    float* ws  = (float*)d_ws;

    const size_t KV = (size_t)BB * NHh * NPAD * HD;      // 7,864,320 halves per tensor
    _Float16* qh  = (_Float16*)ws;
    _Float16* kh  = qh + KV;
    _Float16* vh  = kh + KV;
    _Float16* aoh = vh + KV;                              // MM*DIMM halves
    _Float16* M2g = aoh + (size_t)MM*DIMM;
    _Float16* xh  = M2g + NPAD*64;
    _Float16* wh  = xh + (size_t)MM*DIMM;
    _Float16* pwh = wh + (size_t)NW3*DIMM;

    dim3 b256(256, 1, 1);
    // 40960 (M2) + 786432 (vpad) + 2362368 (converts) = 3189760 = 12460 * 256
    init_all<<<12460, b256, 0, stream>>>(x, qkv_w, proj_w, M2g, vh, xh, wh, pwh);

    dim3 g1(NW3/128, (MM + 127)/128, 1);                 // 18 x 73
    qkv_gemm<<<g1, b256, 0, stream>>>(xh, wh, qh, kh, vh);

    attn_fused<<<dim3(1920,1,1), b256, 0, stream>>>(qh, kh, vh, tkv, tkh, tvv, tvh, M2g, aoh);

    dim3 g3(DIMM/128, (MM + 127)/128, 1);                // 6 x 73
    proj_gemm<<<g3, b256, 0, stream>>>(aoh, pwh, proj_b, out);
}

// Round 16
// 432.970 us; speedup vs baseline: 1.2469x; 1.2469x over previous
//
#include <hip/hip_runtime.h>

// Attention_11845519803093 — R22: R20 revert + BK=64 staged GEMMs.
//   * R21's no-LDS GEMM reverted: GEMM row-fragments are lane-strided (1.5KB
//     apart) -> 16 cache lines per wave-load, ~8x L2 requests. LDS staging is
//     the coalescer; it stays.
//   * gemm128f2: K-step 64 (thread stages 64B A + 64B B, coalesced), MFMAs in
//     two half-K passes (only 8 frags live -> same VGPR profile as BK=32).
//     Barriers per block halved (48 -> 24). LDS 36.9KB, (256,3).
//   * attn = R20 verbatim (srel-hoist, slim last tile, (256,2), VGPR 128).
// ws layout: qh | kh | vh | aoh | M2 | xh | wh | pwh

#define BB    16
#define NNq   577
#define DIMM  768
#define NHh   12
#define HD    64
#define MM    9232
#define QT    64
#define KT    64
#define NPAD  640
#define NW3   2304

typedef _Float16 h8 __attribute__((ext_vector_type(8)));
typedef _Float16 h4 __attribute__((ext_vector_type(4)));
typedef float    f4 __attribute__((ext_vector_type(4)));

__device__ inline h8 pack8(float4 a, float4 b) {
    h8 r;
    r[0]=(_Float16)a.x; r[1]=(_Float16)a.y; r[2]=(_Float16)a.z; r[3]=(_Float16)a.w;
    r[4]=(_Float16)b.x; r[5]=(_Float16)b.y; r[6]=(_Float16)b.z; r[7]=(_Float16)b.w;
    return r;
}

// ---------------------------------------------------------------- merged init
__global__ void init_all(const float* __restrict__ x, const float* __restrict__ w,
                         const float* __restrict__ pw,
                         _Float16* __restrict__ M2g, _Float16* __restrict__ vh,
                         _Float16* __restrict__ xh, _Float16* __restrict__ wh,
                         _Float16* __restrict__ pwh)
{
    const size_t id = (size_t)blockIdx.x*256 + threadIdx.x;
    if (id < NPAD*64) {
        const int key = (int)id >> 6, bin = (int)id & 63;
        int vb = 255, hb = 255;
        if (key == 0)      { vb = 24; hb = 49; }
        else if (key < NNq){ const int kq = key-1, kv = kq/24; vb = kv; hb = 25 + (kq - kv*24); }
        M2g[bin*NPAD + key] =
            ((key < NNq) && (bin==vb || bin==hb || bin==50)) ? (_Float16)1.f : (_Float16)0.f;
        return;
    }
    const size_t vid = id - NPAD*64;
    if (vid < (size_t)BB*NHh*HD*64) {
        const int head = (int)(vid >> 12);
        const int rem  = (int)vid & 4095;
        const int d    = rem >> 6;
        const int col  = 576 + (rem & 63);
        vh[(size_t)head*(HD*NPAD) + (size_t)d*NPAD + col] = (_Float16)0.f;
        return;
    }
    const size_t cid = vid - (size_t)BB*NHh*HD*64;
    const size_t NX = (size_t)MM*DIMM/4;
    const size_t NW = (size_t)NW3*DIMM/4;
    const size_t NP = (size_t)DIMM*DIMM/4;
    const float4* src; h4* dst; size_t j;
    if (cid < NX)            { src = (const float4*)x;  dst = (h4*)xh;  j = cid; }
    else if (cid < NX+NW)    { src = (const float4*)w;  dst = (h4*)wh;  j = cid - NX; }
    else if (cid < NX+NW+NP) { src = (const float4*)pw; dst = (h4*)pwh; j = cid - NX - NW; }
    else return;
    const float4 v = src[j];
    h4 hh; hh[0]=(_Float16)v.x; hh[1]=(_Float16)v.y; hh[2]=(_Float16)v.z; hh[3]=(_Float16)v.w;
    dst[j] = hh;
}

// ---------------------------------------------------------------- BK=64 staged fp16 GEMM core
template <typename F>
__device__ __forceinline__ void gemm128f2(const _Float16* __restrict__ Ah_g,
                                          const _Float16* __restrict__ Bh_g,
                                          F epi)
{
    __shared__ _Float16 Ah[128][72], Bh[128][72];
    const int t  = threadIdx.x;
    const int wv = t >> 6, lane = t & 63, lo = lane & 15, g = lane >> 4;
    const int gb = g << 3;
    const int wm = (wv >> 1) << 6, wn = (wv & 1) << 6;
    const int bm = blockIdx.y << 7, bn = blockIdx.x << 7;
    f4 acc[4][4] = {};
    const int lr = t >> 1;
    const int lc = (t & 1) << 5;          // 0 or 32
    const int am = bm + lr;
    const bool aok = am < MM;
    const _Float16* arh = Ah_g + (size_t)(aok ? am : 0) * DIMM + lc;
    const _Float16* brh = Bh_g + (size_t)(bn + lr) * DIMM + lc;

    for (int k0 = 0; k0 < DIMM; k0 += 64) {
        h8 a0 = {}, a1 = {}, a2 = {}, a3 = {};
        if (aok) {
            a0 = *(const h8*)(arh + k0);      a1 = *(const h8*)(arh + k0 + 8);
            a2 = *(const h8*)(arh + k0 + 16); a3 = *(const h8*)(arh + k0 + 24);
        }
        const h8 b0 = *(const h8*)(brh + k0),      b1 = *(const h8*)(brh + k0 + 8);
        const h8 b2 = *(const h8*)(brh + k0 + 16), b3 = *(const h8*)(brh + k0 + 24);
        __syncthreads();
        *(h8*)&Ah[lr][lc]    = a0; *(h8*)&Ah[lr][lc+8]  = a1;
        *(h8*)&Ah[lr][lc+16] = a2; *(h8*)&Ah[lr][lc+24] = a3;
        *(h8*)&Bh[lr][lc]    = b0; *(h8*)&Bh[lr][lc+8]  = b1;
        *(h8*)&Bh[lr][lc+16] = b2; *(h8*)&Bh[lr][lc+24] = b3;
        __syncthreads();
        // half-K pass 0 (cols 0..31): 8 frags live
        {
            h8 fah[4], fbh[4];
            #pragma unroll
            for (int i = 0; i < 4; ++i) {
                fah[i] = *(const h8*)&Ah[wm + 16*i + lo][gb];
                fbh[i] = *(const h8*)&Bh[wn + 16*i + lo][gb];
            }
            #pragma unroll
            for (int mi = 0; mi < 4; ++mi) {
                #pragma unroll
                for (int ni = 0; ni < 4; ++ni)
                    acc[mi][ni] = __builtin_amdgcn_mfma_f32_16x16x32_f16(fah[mi], fbh[ni], acc[mi][ni], 0, 0, 0);
            }
        }
        // half-K pass 1 (cols 32..63)
        {
            h8 fah[4], fbh[4];
            #pragma unroll
            for (int i = 0; i < 4; ++i) {
                fah[i] = *(const h8*)&Ah[wm + 16*i + lo][32 + gb];
                fbh[i] = *(const h8*)&Bh[wn + 16*i + lo][32 + gb];
            }
            #pragma unroll
            for (int mi = 0; mi < 4; ++mi) {
                #pragma unroll
                for (int ni = 0; ni < 4; ++ni)
                    acc[mi][ni] = __builtin_amdgcn_mfma_f32_16x16x32_f16(fah[mi], fbh[ni], acc[mi][ni], 0, 0, 0);
            }
        }
    }
    epi(acc, bm, bn, wm, wn, lo, g);
}

// ---------------------------------------------------------------- QKV GEMM
__global__ __launch_bounds__(256, 3)
void qkv_gemm(const _Float16* __restrict__ xh, const _Float16* __restrict__ wh,
              _Float16* __restrict__ qh, _Float16* __restrict__ kh, _Float16* __restrict__ vh)
{
    gemm128f2(xh, wh, [=](f4 (&acc)[4][4], int bm, int bn, int wm, int wn, int lo, int g) {
        const int three = bn / 768;
        const int cb    = bn - three * 768;
        #pragma unroll
        for (int mi = 0; mi < 4; ++mi) {
            #pragma unroll
            for (int reg = 0; reg < 4; ++reg) {
                const int m = bm + wm + 16*mi + 4*g + reg;
                if (m >= MM) continue;
                const int b_ = m / NNq;
                const int n_ = m - b_ * NNq;
                #pragma unroll
                for (int ni = 0; ni < 4; ++ni) {
                    const int n  = cb + wn + 16*ni + lo;
                    const int hh = n >> 6;
                    const int d  = n & 63;
                    if (three == 0) {
                        // Q scaled 0.125 * log2(e) for the exp2 path
                        qh[((size_t)(b_*NHh + hh)*NPAD + n_)*HD + d] =
                            (_Float16)(acc[mi][ni][reg] * 0.18033688f);
                    } else if (three == 1) {
                        kh[((size_t)(b_*NHh + hh)*NPAD + n_)*HD + d] = (_Float16)acc[mi][ni][reg];
                    } else {
                        vh[((size_t)(b_*NHh + hh)*HD + d)*NPAD + n_] = (_Float16)acc[mi][ni][reg];
                    }
                }
            }
        }
    });
}

// ---------------------------------------------------------------- proj GEMM
__global__ __launch_bounds__(256, 3)
void proj_gemm(const _Float16* __restrict__ aoh, const _Float16* __restrict__ pwh,
               const float* __restrict__ bias, float* __restrict__ out)
{
    gemm128f2(aoh, pwh, [=](f4 (&acc)[4][4], int bm, int bn, int wm, int wn, int lo, int g) {
        #pragma unroll
        for (int ni = 0; ni < 4; ++ni) {
            const int n  = bn + wn + 16*ni + lo;
            const float bb = bias[n];
            #pragma unroll
            for (int mi = 0; mi < 4; ++mi) {
                #pragma unroll
                for (int reg = 0; reg < 4; ++reg) {
                    const int m = bm + wm + 16*mi + 4*g + reg;
                    if (m >= MM) continue;
                    out[(size_t)m*DIMM + n] = acc[mi][ni][reg] + bb;
                }
            }
        }
    });
}

// ---------------------------------------------------------------- fused attention (R20 verbatim)
__global__ __launch_bounds__(256, 2)
void attn_fused(const _Float16* __restrict__ qh,
                const _Float16* __restrict__ kh, const _Float16* __restrict__ vh,
                const float* __restrict__ tkv, const float* __restrict__ tkh,
                const float* __restrict__ tvv, const float* __restrict__ tvh,
                const _Float16* __restrict__ M2g,
                _Float16* __restrict__ aoh)
{
    __shared__ __align__(16) char smem[34048];
    _Float16 (*qrelS)[72] = (_Float16(*)[72])(smem);
    _Float16 (*Pt)[72]    = (_Float16(*)[72])(smem + 9216);
    float    (*TvS)[65]   = (float(*)[65])(smem + 18432);
    float    (*binsS)[52] = (float(*)[52])(smem);

    const int t    = threadIdx.x;
    const int w    = t >> 6;
    const int lane = t & 63;
    const int lo   = lane & 15;
    const int g    = lane >> 4;
    const int gb   = g << 3;

    const int blk = blockIdx.x;            // 0..1919
    const int x8  = blk & 7;
    const int r_  = blk >> 3;              // 0..239
    const int hq  = r_ / 10;               // 0..23
    const int qt  = r_ - hq*10;            // 0..9
    const int bh  = x8 + (hq << 3);        // head 0..191
    const int qt0 = qt * QT;
    const int qrow = 16*w + 4*g;
    const _Float16* qp = qh + (size_t)bh * (NPAD*HD);
    const _Float16* kp = kh + (size_t)bh * (NPAD*HD);
    const _Float16* vp = vh + (size_t)bh * (HD*NPAD);

    for (int e = t; e < 60*64; e += 256) {
        const int r = e >> 6, d = e & 63;
        TvS[r][d] = (r < 30) ? tvv[r*HD + d] : tvh[(r-30)*HD + d];
    }

    const h8 a0 = *(const h8*)(qp + (size_t)(qt0 + 16*w + lo)*HD + gb);
    const h8 a1 = *(const h8*)(qp + (size_t)(qt0 + 16*w + lo)*HD + 32 + gb);

    {
        f4 qacc[4] = {f4{0,0,0,0}, f4{0,0,0,0}, f4{0,0,0,0}, f4{0,0,0,0}};
        #pragma unroll
        for (int c = 0; c < 4; ++c) {
            const int r16 = 16*c + lo;
            const float* src = (r16 < 30) ? (tkv + r16*HD) : (tkh + (r16-30)*HD);
            h8 tb0 = {}, tb1 = {};
            if (r16 < 60) {
                tb0 = pack8(*(const float4*)(src + gb),      *(const float4*)(src + gb + 4));
                tb1 = pack8(*(const float4*)(src + 32 + gb), *(const float4*)(src + 32 + gb + 4));
            }
            qacc[c] = __builtin_amdgcn_mfma_f32_16x16x32_f16(a0, tb0, qacc[c], 0, 0, 0);
            qacc[c] = __builtin_amdgcn_mfma_f32_16x16x32_f16(a1, tb1, qacc[c], 0, 0, 0);
        }
        #pragma unroll
        for (int c = 0; c < 4; ++c) {
            #pragma unroll
            for (int i = 0; i < 4; ++i)
                qrelS[qrow + i][16*c + lo] = (_Float16)qacc[c][i];
        }
    }
    // NO barrier: gather below reads only this wave's own rows.

    int qv_[4], qh_[4];
    bool q0_[4];
    #pragma unroll
    for (int i = 0; i < 4; ++i) {
        const int qgl = qt0 + qrow + i;
        q0_[i] = (qgl == 0);
        int qq = qgl - 1; if (qq < 0) qq = 0;
        qv_[i] = qq / 24;
        qh_[i] = qq - qv_[i]*24;
    }

    f4 o_acc [4] = {f4{0,0,0,0}, f4{0,0,0,0}, f4{0,0,0,0}, f4{0,0,0,0}};
    f4 binacc[4] = {f4{0,0,0,0}, f4{0,0,0,0}, f4{0,0,0,0}, f4{0,0,0,0}};

    // ================= main loop: 9 full tiles (keys 0..575) =================
    for (int kt0 = 0; kt0 < 576; kt0 += KT) {
        h8 kb0[4], kb1[4], v0r[4], v1r[4], m20[4], m21[4];
        #pragma unroll
        for (int c = 0; c < 4; ++c) {
            const int key = kt0 + 16*c + lo;
            kb0[c] = *(const h8*)(kp + (size_t)key*HD + gb);
            kb1[c] = *(const h8*)(kp + (size_t)key*HD + 32 + gb);
            const int dd = 16*c + lo;
            v0r[c] = *(const h8*)(vp + (size_t)dd*NPAD + kt0 + gb);
            v1r[c] = *(const h8*)(vp + (size_t)dd*NPAD + kt0 + 32 + gb);
            m20[c] = *(const h8*)(M2g + (size_t)dd*NPAD + kt0 + gb);
            m21[c] = *(const h8*)(M2g + (size_t)dd*NPAD + kt0 + 32 + gb);
        }
        // ---- srel-hoist: LDS gather BEFORE the MFMAs (hides under vmcnt) ----
        float srel[4][4];
        #pragma unroll
        for (int c = 0; c < 4; ++c) {
            const int key = kt0 + 16*c + lo;
            int kk = key - 1; if (kk < 0) kk = 0;
            const int kv  = kk / 24;
            const int kh2 = kk - kv*24;
            const bool kz = (key == 0);
            #pragma unroll
            for (int i = 0; i < 4; ++i) {
                int colv, colh;
                if (kz || q0_[i]) { colv = 0; colh = 30; }
                else {
                    int dv = kv  - qv_[i]; dv = min(14, max(-14, dv));
                    int dh = kh2 - qh_[i]; dh = min(14, max(-14, dh));
                    colv = dv + 15;
                    colh = 45 + dh;
                }
                srel[c][i] = (float)qrelS[qrow+i][colv] + (float)qrelS[qrow+i][colh];
            }
        }
        f4 Sc[4];
        #pragma unroll
        for (int c = 0; c < 4; ++c) {
            f4 acc = f4{0,0,0,0};
            acc = __builtin_amdgcn_mfma_f32_16x16x32_f16(a0, kb0[c], acc, 0, 0, 0);
            acc = __builtin_amdgcn_mfma_f32_16x16x32_f16(a1, kb1[c], acc, 0, 0, 0);
            Sc[c] = acc;
        }
        #pragma unroll
        for (int c = 0; c < 4; ++c) {
            #pragma unroll
            for (int i = 0; i < 4; ++i) {
                const float p = exp2f(Sc[c][i] + srel[c][i]);
                Pt[qrow+i][16*c + lo] = (_Float16)p;
            }
        }
        const h8 p0 = *(const h8*)&Pt[16*w + lo][gb];
        const h8 p1 = *(const h8*)&Pt[16*w + lo][32 + gb];
        #pragma unroll
        for (int c = 0; c < 4; ++c) {
            binacc[c] = __builtin_amdgcn_mfma_f32_16x16x32_f16(p0, m20[c], binacc[c], 0, 0, 0);
            binacc[c] = __builtin_amdgcn_mfma_f32_16x16x32_f16(p1, m21[c], binacc[c], 0, 0, 0);
        }
        #pragma unroll
        for (int c = 0; c < 4; ++c) {
            o_acc[c] = __builtin_amdgcn_mfma_f32_16x16x32_f16(p0, v0r[c], o_acc[c], 0, 0, 0);
            o_acc[c] = __builtin_amdgcn_mfma_f32_16x16x32_f16(p1, v1r[c], o_acc[c], 0, 0, 0);
        }
    }

    // ================= slim last tile: kt0 = 576, 1 valid key =================
    {
        const int kt0 = 576;
        h8 kb0_, kb1_, v0r[4], v1r[4], m20[4], m21[4];
        kb0_ = *(const h8*)(kp + (size_t)(kt0 + lo)*HD + gb);
        kb1_ = *(const h8*)(kp + (size_t)(kt0 + lo)*HD + 32 + gb);
        #pragma unroll
        for (int c = 0; c < 4; ++c) {
            const int dd = 16*c + lo;
            v0r[c] = *(const h8*)(vp + (size_t)dd*NPAD + kt0 + gb);
            v1r[c] = *(const h8*)(vp + (size_t)dd*NPAD + kt0 + 32 + gb);
            m20[c] = *(const h8*)(M2g + (size_t)dd*NPAD + kt0 + gb);
            m21[c] = *(const h8*)(M2g + (size_t)dd*NPAD + kt0 + 32 + gb);
        }
        float srel0[4];
        {
            const int key = kt0 + lo;
            int kk = key - 1; if (kk < 0) kk = 0;
            const int kv  = kk / 24;
            const int kh2 = kk - kv*24;
            #pragma unroll
            for (int i = 0; i < 4; ++i) {
                int colv, colh;
                if (q0_[i]) { colv = 0; colh = 30; }
                else {
                    int dv = kv  - qv_[i]; dv = min(14, max(-14, dv));
                    int dh = kh2 - qh_[i]; dh = min(14, max(-14, dh));
                    colv = dv + 15;
                    colh = 45 + dh;
                }
                srel0[i] = (float)qrelS[qrow+i][colv] + (float)qrelS[qrow+i][colh];
            }
        }
        f4 Sc0 = f4{0,0,0,0};
        Sc0 = __builtin_amdgcn_mfma_f32_16x16x32_f16(a0, kb0_, Sc0, 0, 0, 0);
        Sc0 = __builtin_amdgcn_mfma_f32_16x16x32_f16(a1, kb1_, Sc0, 0, 0, 0);
        {
            const bool ok = (kt0 + lo) < NNq;
            #pragma unroll
            for (int i = 0; i < 4; ++i) {
                const float p = ok ? exp2f(Sc0[i] + srel0[i]) : 0.f;
                Pt[qrow+i][lo] = (_Float16)p;
            }
            #pragma unroll
            for (int c = 1; c < 4; ++c) {
                #pragma unroll
                for (int i = 0; i < 4; ++i)
                    Pt[qrow+i][16*c + lo] = (_Float16)0.f;
            }
        }
        const h8 p0 = *(const h8*)&Pt[16*w + lo][gb];
        const h8 p1 = *(const h8*)&Pt[16*w + lo][32 + gb];
        #pragma unroll
        for (int c = 0; c < 4; ++c) {
            binacc[c] = __builtin_amdgcn_mfma_f32_16x16x32_f16(p0, m20[c], binacc[c], 0, 0, 0);
            binacc[c] = __builtin_amdgcn_mfma_f32_16x16x32_f16(p1, m21[c], binacc[c], 0, 0, 0);
        }
        #pragma unroll
        for (int c = 0; c < 4; ++c) {
            o_acc[c] = __builtin_amdgcn_mfma_f32_16x16x32_f16(p0, v0r[c], o_acc[c], 0, 0, 0);
            o_acc[c] = __builtin_amdgcn_mfma_f32_16x16x32_f16(p1, v1r[c], o_acc[c], 0, 0, 0);
        }
    }

    // ---- epilogue ----
    __syncthreads();
    #pragma unroll
    for (int c = 0; c < 4; ++c) {
        const int bc = 16*c + lo;
        if (bc <= 50) {
            #pragma unroll
            for (int i = 0; i < 4; ++i) binsS[qrow+i][bc] = binacc[c][i];
        }
    }
    __syncthreads();

    const int b_ = bh / NHh;
    const int h_ = bh - b_*NHh;
    #pragma unroll
    for (int i = 0; i < 4; ++i) {
        const int qr  = qrow + i;
        const int qgl = qt0 + qr;
        if (qgl >= NNq) continue;
        const float l    = binsS[qr][50];
        const float invl = 1.f / l;
        float o[4] = {o_acc[0][i], o_acc[1][i], o_acc[2][i], o_acc[3][i]};
        if (qgl == 0) {
            #pragma unroll
            for (int c = 0; c < 4; ++c) {
                const int d = 16*c + lo;
                o[c] += l * (TvS[0][d] + TvS[30][d]);
            }
        } else {
            #pragma unroll
            for (int bin = 0; bin < 24; ++bin) {
                const float wq = binsS[qr][bin];
                int dv = bin - qv_[i]; dv = min(14, max(-14, dv));
                #pragma unroll
                for (int c = 0; c < 4; ++c) o[c] += wq * TvS[dv+15][16*c + lo];
            }
            {
                const float wq = binsS[qr][24];
                #pragma unroll
                for (int c = 0; c < 4; ++c) o[c] += wq * TvS[0][16*c + lo];
            }
            #pragma unroll
            for (int bin = 0; bin < 24; ++bin) {
                const float wq = binsS[qr][25+bin];
                int dh = bin - qh_[i]; dh = min(14, max(-14, dh));
                #pragma unroll
                for (int c = 0; c < 4; ++c) o[c] += wq * TvS[45+dh][16*c + lo];
            }
            {
                const float wq = binsS[qr][49];
                #pragma unroll
                for (int c = 0; c < 4; ++c) o[c] += wq * TvS[30][16*c + lo];
            }
        }
        _Float16* dst = aoh + (size_t)(b_*NNq + qgl)*DIMM + h_*HD;
        #pragma unroll
        for (int c = 0; c < 4; ++c) dst[16*c + lo] = (_Float16)(o[c] * invl);
    }
}

// ---------------------------------------------------------------- launcher
extern "C" void kernel_launch(void* const* d_in, const int* in_sizes, int n_in,
                              void* d_out, int out_size, void* d_ws, size_t ws_size,
                              hipStream_t stream)
{
    const float* x      = (const float*)d_in[0];
    const float* qkv_w  = (const float*)d_in[1];
    const float* proj_w = (const float*)d_in[2];
    const float* proj_b = (const float*)d_in[3];
    const float* tkv    = (const float*)d_in[4];
    const float* tkh    = (const float*)d_in[5];
    const float* tvv    = (const float*)d_in[6];
    const float* tvh    = (const float*)d_in[7];
    float* out = (float*)d_out;
    float* ws  = (float*)d_ws;

    const size_t KV = (size_t)BB * NHh * NPAD * HD;      // 7,864,320 halves per tensor
    _Float16* qh  = (_Float16*)ws;
    _Float16* kh  = qh + KV;
    _Float16* vh  = kh + KV;
    _Float16* aoh = vh + KV;                              // MM*DIMM halves
    _Float16* M2g = aoh + (size_t)MM*DIMM;
    _Float16* xh  = M2g + NPAD*64;
    _Float16* wh  = xh + (size_t)MM*DIMM;
    _Float16* pwh = wh + (size_t)NW3*DIMM;

    dim3 b256(256, 1, 1);
    // 40960 (M2) + 786432 (vpad) + 2362368 (converts) = 3189760 = 12460 * 256
    init_all<<<12460, b256, 0, stream>>>(x, qkv_w, proj_w, M2g, vh, xh, wh, pwh);

    dim3 g1(NW3/128, (MM + 127)/128, 1);                 // 18 x 73
    qkv_gemm<<<g1, b256, 0, stream>>>(xh, wh, qh, kh, vh);

    attn_fused<<<dim3(1920,1,1), b256, 0, stream>>>(qh, kh, vh, tkv, tkh, tvv, tvh, M2g, aoh);

    dim3 g3(DIMM/128, (MM + 127)/128, 1);                // 6 x 73
    proj_gemm<<<g3, b256, 0, stream>>>(aoh, pwh, proj_b, out);
}